// Round 6
// baseline (570.462 us; speedup 1.0000x reference)
//
#include <hip/hip_runtime.h>

// GPTQ 4-bit quantized linear, MI355X (gfx950). fp32 in/out.
// out[M,N] = x[M,K] @ dequant(qweight)[K,N] + bias[N]
// M=4096, K=4096, N=11008, groupsize=128.
//
// Round 11: minimal-sync schedule. 8 -> 4 barriers/iter; explicit lgkmcnt(0)
// drains removed (compiler emits counted lgkmcnt per ds_read->MFMA dep;
// every read is consumed by its own phase's MFMAs, so reads are drained
// before the wave reaches the phase-end barrier -- race proof preserved).
// VMW4 moved after the MFMA cluster in p4/p8 (vmcnt wait hides under MFMA).
// Surviving barriers, each tied to exactly one writer-after-reader hazard:
//   p2-end : p3/p4 STAGE buf0-B  vs all waves' buf0-B reads (consumed p1/p2)
//   p4-mid : publishes vmcnt drain of buf1 A+B; gates p5/p6 STAGE buf0-A
//            (buf0-A reads consumed by p1..p3 MFMAs, ordered by this barrier)
//   p6-end : p7/p8 STAGE buf1-B  vs buf1-B reads (consumed p5/p6)
//   p8-mid : publishes drain of buf0; gates next-iter p1/p2 STAGE buf1-A
// Read placement + frag live-set IDENTICAL to round 10 (VGPR 128, no spills).

#define TM 4096
#define TK 4096
#define TN 11008
#define GS 128
#define NG (TK / GS)
#define QZC (TN / 8)

// ---- phase-2 geometry (256x256 tile, BK=64, 8 waves / 512 threads) ----
#define BM2 256
#define BN2 256
#define BK2 64
#define NKT (TK / BK2)                    // 64 K-tiles
#define NBN (TN / BN2)                    // 43
#define GRID2 ((TM / BM2) * (TN / BN2))   // 16*43 = 688 (== 0 mod 8)

// ---- dequant geometry ----
#define DQN 256                           // n-columns per block
#define DQROW 136                         // LDS row stride in shorts (272 B)

// ---- legacy 128^2 geometry (fallback kernel) ----
#define BM 128
#define BN 128
#define BK 32

#define XB_BYTES ((size_t)TM * TK * 2)            // 33,554,432
#define WT_BYTES ((size_t)TN * TK * 2)            // 90,177,536
#define WS_NEED  (XB_BYTES + WT_BYTES)

typedef __attribute__((ext_vector_type(8))) short short8;
typedef __attribute__((ext_vector_type(4))) float floatx4;

union S8U { short8 v; unsigned u[4]; };

__device__ __forceinline__ unsigned short f2bf_rn(float f) {
    unsigned u = __builtin_bit_cast(unsigned, f);
    u += 0x7FFFu + ((u >> 16) & 1u);
    return (unsigned short)(u >> 16);
}
__device__ __forceinline__ unsigned pack2(float a, float b) {
    return (unsigned)f2bf_rn(a) | ((unsigned)f2bf_rn(b) << 16);
}

// ---------------- Phase 1a: X fp32 -> bf16 ----------------
__global__ __launch_bounds__(256)
void conv_x(const float* __restrict__ X, unsigned short* __restrict__ Xb)
{
    const size_t i = ((size_t)blockIdx.x * 256 + threadIdx.x) * 8;  // 8 floats/thread
    floatx4 v0 = *(const floatx4*)(X + i);
    floatx4 v1 = *(const floatx4*)(X + i + 4);
    S8U o;
    o.u[0] = pack2(v0[0], v0[1]); o.u[1] = pack2(v0[2], v0[3]);
    o.u[2] = pack2(v1[0], v1[1]); o.u[3] = pack2(v1[2], v1[3]);
    *(short8*)(Xb + i) = o.v;
}

// ---------------- Phase 1b: dequant qweight -> bf16 W^T[N][K] ----------------
// Coalesced QW reads (lane-consecutive n) + LDS transpose (272 B row stride)
// + 256B-per-16-lane output store pattern. (round-9 verified)
__global__ __launch_bounds__(256)
void dequant_w(const int* __restrict__ QW, const int* __restrict__ QZ,
               const float* __restrict__ SC, unsigned short* __restrict__ Wt)
{
    __shared__ __align__(16) short lds[DQN * DQROW];   // 69,632 B

    const int g  = blockIdx.x % NG;           // k-group
    const int n0 = (blockIdx.x / NG) * DQN;   // n-tile base
    const int t  = threadIdx.x;
    const int n  = n0 + t;

    const float s = SC[(size_t)g * TN + n];
    const int z = (int)(((unsigned)QZ[g * QZC + (n >> 3)] >> ((n & 7) * 4)) & 15u) + 1;
    const float zc = -s * (float)z;

    #pragma unroll
    for (int i = 0; i < 16; ++i) {
        const unsigned q = (unsigned)QW[(size_t)(g * 16 + i) * TN + n];  // coalesced
        const unsigned qe = q & 0x0F0F0F0Fu;          // nibbles 0,2,4,6
        const unsigned qo = (q >> 4) & 0x0F0F0F0Fu;   // nibbles 1,3,5,7
        S8U vv;
        #pragma unroll
        for (int jj = 0; jj < 4; ++jj) {
            const float w0 = (float)((qe >> (8 * jj)) & 0xFFu);
            const float w1 = (float)((qo >> (8 * jj)) & 0xFFu);
            vv.u[jj] = pack2(fmaf(w0, s, zc), fmaf(w1, s, zc));
        }
        *(short8*)(lds + t * DQROW + i * 8) = vv.v;
    }
    __syncthreads();

    const int c  = t & 15;          // pack chunk within group
    const int r0 = t >> 4;          // row base
    #pragma unroll
    for (int j = 0; j < 16; ++j) {
        const int nl = r0 + 16 * j;
        const short8 v = *(const short8*)(lds + nl * DQROW + c * 8);
        *(short8*)(Wt + (size_t)(n0 + nl) * TK + g * 128 + c * 8) = v;
    }
}

// ---------------- Phase 2: 256^2 8-phase bf16 GEMM ----------------
#define GLDS(gp, lp) __builtin_amdgcn_global_load_lds( \
    (const __attribute__((address_space(1))) void*)(gp), \
    (__attribute__((address_space(3))) void*)(lp), 16, 0, 0)

// op: 0=A, 1=B. half: 0 = rows [0,128), 1 = rows [128,256).
#define STAGE(op, gptr, buf, half, kt) do {                                   \
    const unsigned short* _g = (gptr) + (size_t)(half) * 128 * TK             \
                                      + (size_t)(kt) * BK2;                   \
    short* _l = &sh[buf][op][(half) * 8192 + ldst];                           \
    GLDS(_g, _l);                                                             \
    GLDS(_g + (size_t)64 * TK, _l + 4096);                                    \
} while (0)

// swizzled fragment reads: global 16B-chunk c sits at LDS slot c ^ (row&7)
#define RDA(buf, mi, ks) (*(const short8*)&sh[buf][0][ \
    (wr * 128 + (mi) * 16 + l16) * 64 + ((((ks) << 2) | quad) ^ swz) * 8])
#define RDB(buf, ni, ks) (*(const short8*)&sh[buf][1][ \
    (wc * 64 + (ni) * 16 + l16) * 64 + ((((ks) << 2) | quad) ^ swz) * 8])

#define BARRIER __builtin_amdgcn_s_barrier()
#define VMW4  asm volatile("s_waitcnt vmcnt(4)" ::: "memory")

template<int MI0, int NI0>
__device__ __forceinline__ void mfma_quad(floatx4 (&acc)[8][4],
                                          const short8 (&a)[4][2],
                                          const short8 (&b)[4][2]) {
    __builtin_amdgcn_s_setprio(1);
    #pragma unroll
    for (int m = 0; m < 4; ++m)
        #pragma unroll
        for (int n = 0; n < 2; ++n)
            #pragma unroll
            for (int ks = 0; ks < 2; ++ks)
                acc[MI0 + m][NI0 + n] = __builtin_amdgcn_mfma_f32_16x16x32_bf16(
                    a[m][ks], b[NI0 + n][ks], acc[MI0 + m][NI0 + n], 0, 0, 0);
    __builtin_amdgcn_s_setprio(0);
}

__global__ __launch_bounds__(512, 2)
void gemm_8ph(const unsigned short* __restrict__ A,   // bf16 [TM][TK]
              const unsigned short* __restrict__ Bt,  // bf16 [TN][TK]
              const float* __restrict__ BIAS,         // fp32 [TN]
              float* __restrict__ OUT)                // fp32 [TM][TN]
{
    __shared__ __align__(16) short sh[2][2][BM2 * BK2];   // 128 KiB

    const int tid  = threadIdx.x;
    const int lane = tid & 63;
    const int wave = tid >> 6;          // 0..7
    const int wr   = wave >> 2;         // 0..1 (M half)
    const int wc   = wave & 3;          // 0..3 (N quarter)
    const int quad = lane >> 4;
    const int l16  = lane & 15;
    const int swz  = l16 & 7;

    // T1: bijective XCD chunk swizzle (688 = 8 * 86); bn fastest -> A reuse in L2
    const int bid  = blockIdx.x;
    const int wgid = (bid & 7) * (GRID2 / 8) + (bid >> 3);
    const int bm = wgid / NBN;
    const int bn = wgid % NBN;

    // staging: LDS dest linear (base + lane*16B); global source pre-swizzled
    const int srow = wave * 8 + (lane >> 3);            // 0..63
    const int scol = 8 * ((lane & 7) ^ (lane >> 3));    // elements
    const unsigned short* Ag = A  + (size_t)(bm * BM2 + srow) * TK + scol;
    const unsigned short* Bg = Bt + (size_t)(bn * BN2 + srow) * TK + scol;
    const int ldst = wave * 512 + lane * 8;             // shorts

    floatx4 acc[8][4];
    #pragma unroll
    for (int i = 0; i < 8; ++i)
        #pragma unroll
        for (int j = 0; j < 4; ++j)
            acc[i][j] = (floatx4){0.f, 0.f, 0.f, 0.f};

    short8 a[4][2], b[4][2];

    // prologue: K-tile 0 full -> buf0; K-tile 1 B-halves -> buf1
    STAGE(0, Ag, 0, 0, 0); STAGE(0, Ag, 0, 1, 0);
    STAGE(1, Bg, 0, 0, 0); STAGE(1, Bg, 0, 1, 0);
    STAGE(1, Bg, 1, 0, 1); STAGE(1, Bg, 1, 1, 1);
    VMW4;       // drain K-tile 0's 8 loads; 4 (t1 B) stay in flight
    BARRIER;

    for (int it = 0; it < NKT / 2; ++it) {
        const int t  = 2 * it;
        const int t2 = (t + 2 < NKT) ? t + 2 : NKT - 1;   // tail stages: garbage,
        const int t3 = (t + 3 < NKT) ? t + 3 : NKT - 1;   // never consumed

        // ======== K-tile t (buf0) ========
        // p1: reads buf0 a03+b01 (consumed by this phase's MFMAs -> drained
        //     before this wave reaches any later barrier); stage Ah0(t+1)->buf1
        #pragma unroll
        for (int m = 0; m < 4; ++m) { a[m][0] = RDA(0, m, 0); a[m][1] = RDA(0, m, 1); }
        #pragma unroll
        for (int n = 0; n < 2; ++n) { b[n][0] = RDB(0, n, 0); b[n][1] = RDB(0, n, 1); }
        STAGE(0, Ag, 1, 0, t + 1);
        mfma_quad<0, 0>(acc, a, b);

        // p2: reads buf0 b23; stage Ah1(t+1)->buf1; END BARRIER: all waves'
        //     buf0-B reads (b01 p1, b23 p2) consumed -> p3/p4 may stage buf0-B
        #pragma unroll
        for (int n = 2; n < 4; ++n) { b[n][0] = RDB(0, n, 0); b[n][1] = RDB(0, n, 1); }
        STAGE(0, Ag, 1, 1, t + 1);
        mfma_quad<0, 2>(acc, a, b);
        BARRIER;

        // p3: reads buf0 a47; stage Bh0(t+2)->buf0-B (safe per p2 barrier)
        #pragma unroll
        for (int m = 0; m < 4; ++m) { a[m][0] = RDA(0, m + 4, 0); a[m][1] = RDA(0, m + 4, 1); }
        STAGE(1, Bg, 0, 0, t2);
        mfma_quad<4, 0>(acc, a, b);

        // p4: stage Bh1(t+2)->buf0-B; MFMA first, then counted drain (leaves
        //     p3/p4's B(t+2) in flight; vmcnt wait hides under the MFMAs);
        //     MID BARRIER publishes buf1 A+B drained AND that every wave's
        //     buf0-A reads (a03 p1, a47 p3) are consumed -> p5/p6 stage buf0-A
        STAGE(1, Bg, 0, 1, t2);
        mfma_quad<4, 2>(acc, a, b);
        VMW4;
        BARRIER;

        // ======== K-tile t+1 (buf1) ========
        // p5: reads buf1 a03+b01; stage Ah0(t+2)->buf0-A
        #pragma unroll
        for (int m = 0; m < 4; ++m) { a[m][0] = RDA(1, m, 0); a[m][1] = RDA(1, m, 1); }
        #pragma unroll
        for (int n = 0; n < 2; ++n) { b[n][0] = RDB(1, n, 0); b[n][1] = RDB(1, n, 1); }
        STAGE(0, Ag, 0, 0, t2);
        mfma_quad<0, 0>(acc, a, b);

        // p6: reads buf1 b23; stage Ah1(t+2)->buf0-A; END BARRIER: buf1-B
        //     reads consumed -> p7/p8 may stage buf1-B
        #pragma unroll
        for (int n = 2; n < 4; ++n) { b[n][0] = RDB(1, n, 0); b[n][1] = RDB(1, n, 1); }
        STAGE(0, Ag, 0, 1, t2);
        mfma_quad<0, 2>(acc, a, b);
        BARRIER;

        // p7: reads buf1 a47; stage Bh0(t+3)->buf1-B
        #pragma unroll
        for (int m = 0; m < 4; ++m) { a[m][0] = RDA(1, m + 4, 0); a[m][1] = RDA(1, m + 4, 1); }
        STAGE(1, Bg, 1, 0, t3);
        mfma_quad<4, 0>(acc, a, b);

        // p8: stage Bh1(t+3)->buf1-B; MFMA; counted drain (drains buf0's
        //     A(t+2)+B(t+2) for next-iter p1; leaves p7/p8's B(t+3));
        //     MID BARRIER publishes + gates next-iter p1/p2 STAGE buf1-A
        STAGE(1, Bg, 1, 1, t3);
        mfma_quad<4, 2>(acc, a, b);
        VMW4;
        BARRIER;
    }

    // epilogue: C/D col=lane&15, row=quad*4+reg (dtype-independent layout)
    const int row0 = bm * BM2 + wr * 128 + quad * 4;
    const int col0 = bn * BN2 + wc * 64 + l16;
    #pragma unroll
    for (int ni = 0; ni < 4; ++ni) {
        const int col = col0 + ni * 16;
        const float bv = BIAS[col];
        #pragma unroll
        for (int mi = 0; mi < 8; ++mi) {
            #pragma unroll
            for (int r = 0; r < 4; ++r) {
                const int row = row0 + mi * 16 + r;
                OUT[(size_t)row * TN + col] = acc[mi][ni][r] + bv;
            }
        }
    }
}

// ---------------- Fallback: fused kernel (known-good, ws too small) ----------
__global__ __launch_bounds__(256)
void gemm_fused_fallback(const float* __restrict__ X, const int* __restrict__ QW,
                         const int* __restrict__ QZ, const float* __restrict__ SC,
                         const float* __restrict__ BIAS, float* __restrict__ OUT)
{
    __shared__ __align__(16) short As[BM * BK];
    __shared__ __align__(16) short Bs[BN * BK];

    const int tid  = threadIdx.x;
    const int lane = tid & 63;
    const int wave = tid >> 6;
    const int bm = blockIdx.x / (TN / BN);
    const int bn = blockIdx.x % (TN / BN);
    const int wm = (wave & 1) * 64;
    const int wn = (wave >> 1) * 64;
    const int quad = lane >> 4;
    const int l16  = lane & 15;

    const int a_r = tid >> 2;
    const int a_c = (tid & 3) * 8;
    const float* agp = X + (size_t)(bm * BM + a_r) * TK + a_c;
    short* alp = As + a_r * BK + a_c;

    const int b_n = tid & 127;
    const int b_p = tid >> 7;
    const int n_g = bn * BN + b_n;
    const int zsh = (n_g & 7) * 4;

    floatx4 acc[4][4];
    #pragma unroll
    for (int i = 0; i < 4; ++i)
        #pragma unroll
        for (int j = 0; j < 4; ++j)
            acc[i][j] = (floatx4){0.f, 0.f, 0.f, 0.f};

    for (int g = 0; g < NG; ++g) {
        const float s = SC[(size_t)g * TN + n_g];
        const int z = (int)(((unsigned)QZ[g * QZC + (n_g >> 3)] >> zsh) & 15u) + 1;
        const float zc = -s * (float)z;

        #pragma unroll
        for (int t = 0; t < GS / BK; ++t) {
            const int k0 = g * GS + t * BK;
            floatx4 v0 = *(const floatx4*)(agp + k0);
            floatx4 v1 = *(const floatx4*)(agp + k0 + 4);
            floatx4 v2 = *(const floatx4*)(agp + (size_t)64 * TK + k0);
            floatx4 v3 = *(const floatx4*)(agp + (size_t)64 * TK + k0 + 4);
            const unsigned q0 = (unsigned)QW[(size_t)(k0 / 8 + b_p)     * TN + n_g];
            const unsigned q1 = (unsigned)QW[(size_t)(k0 / 8 + b_p + 2) * TN + n_g];

            S8U aw0, aw1;
            aw0.u[0] = pack2(v0[0], v0[1]); aw0.u[1] = pack2(v0[2], v0[3]);
            aw0.u[2] = pack2(v1[0], v1[1]); aw0.u[3] = pack2(v1[2], v1[3]);
            aw1.u[0] = pack2(v2[0], v2[1]); aw1.u[1] = pack2(v2[2], v2[3]);
            aw1.u[2] = pack2(v3[0], v3[1]); aw1.u[3] = pack2(v3[2], v3[3]);
            *(short8*)alp = aw0.v;
            *(short8*)(alp + 64 * BK) = aw1.v;

            const unsigned qs[2] = {q0, q1};
            #pragma unroll
            for (int i = 0; i < 2; ++i) {
                const int p = b_p + i * 2;
                const unsigned q = qs[i];
                const unsigned qe = q & 0x0F0F0F0Fu;
                const unsigned qo = (q >> 4) & 0x0F0F0F0Fu;
                S8U vv;
                #pragma unroll
                for (int jj = 0; jj < 4; ++jj) {
                    const float w0 = (float)((qe >> (8 * jj)) & 0xFFu);
                    const float w1 = (float)((qo >> (8 * jj)) & 0xFFu);
                    vv.u[jj] = pack2(fmaf(w0, s, zc), fmaf(w1, s, zc));
                }
                *(short8*)(Bs + b_n * BK + p * 8) = vv.v;
            }

            __syncthreads();
            short8 af[4], bfr[4];
            #pragma unroll
            for (int i = 0; i < 4; ++i) {
                af[i]  = *(const short8*)(As + (wm + i * 16 + l16) * BK + quad * 8);
                bfr[i] = *(const short8*)(Bs + (wn + i * 16 + l16) * BK + quad * 8);
            }
            #pragma unroll
            for (int mi = 0; mi < 4; ++mi)
                #pragma unroll
                for (int ni = 0; ni < 4; ++ni)
                    acc[mi][ni] = __builtin_amdgcn_mfma_f32_16x16x32_bf16(
                        af[mi], bfr[ni], acc[mi][ni], 0, 0, 0);
            __syncthreads();
        }
    }

    const int col0 = bn * BN + wn + l16;
    const int row0 = bm * BM + wm + quad * 4;
    #pragma unroll
    for (int ni = 0; ni < 4; ++ni) {
        const int col = col0 + ni * 16;
        const float bv = BIAS[col];
        #pragma unroll
        for (int mi = 0; mi < 4; ++mi) {
            #pragma unroll
            for (int r = 0; r < 4; ++r) {
                const int row = row0 + mi * 16 + r;
                OUT[(size_t)row * TN + col] = acc[mi][ni][r] + bv;
            }
        }
    }
}

extern "C" void kernel_launch(void* const* d_in, const int* in_sizes, int n_in,
                              void* d_out, int out_size, void* d_ws, size_t ws_size,
                              hipStream_t stream) {
    // Resolve inputs by element count (all distinct); fall back to dict order.
    const void* px = nullptr; const void* pqw = nullptr; const void* pqz = nullptr;
    const void* psc = nullptr; const void* pbi = nullptr;
    for (int i = 0; i < n_in; ++i) {
        switch (in_sizes[i]) {
            case 16777216: px  = d_in[i]; break;  // x
            case 5636096:  pqw = d_in[i]; break;  // qweight
            case 352256:   psc = d_in[i]; break;  // scales
            case 44032:    pqz = d_in[i]; break;  // qzeros
            case 11008:    pbi = d_in[i]; break;  // bias
            default: break;                        // g_idx unused
        }
    }
    if (!px)  px  = d_in[0];
    if (!pqw) pqw = d_in[1];
    if (!pqz) pqz = d_in[2];
    if (!psc) psc = d_in[3];
    if (!pbi) pbi = d_in[5];

    if (ws_size >= WS_NEED) {
        unsigned short* Xb = (unsigned short*)d_ws;
        unsigned short* Wt = (unsigned short*)((char*)d_ws + XB_BYTES);

        conv_x<<<dim3(TM * TK / 8 / 256), 256, 0, stream>>>((const float*)px, Xb);
        dequant_w<<<dim3(NG * (TN / DQN)), 256, 0, stream>>>(
            (const int*)pqw, (const int*)pqz, (const float*)psc, Wt);
        gemm_8ph<<<dim3(GRID2), 512, 0, stream>>>(
            Xb, Wt, (const float*)pbi, (float*)d_out);
    } else {
        gemm_fused_fallback<<<dim3((TM / BM) * (TN / BN)), 256, 0, stream>>>(
            (const float*)px, (const int*)pqw, (const int*)pqz,
            (const float*)psc, (const float*)pbi, (float*)d_out);
    }
}

// Round 7
// 562.845 us; speedup vs baseline: 1.0135x; 1.0135x over previous
//
#include <hip/hip_runtime.h>

// GPTQ 4-bit quantized linear, MI355X (gfx950). fp32 in/out.
// out[M,N] = x[M,K] @ dequant(qweight)[K,N] + bias[N]
// M=4096, K=4096, N=11008, groupsize=128.
//
// Round 12 = exact revert to round 10 (session best: gemm 315 us, e2e 557 us).
// Round 11 (4 barriers/iter, lgkm pins removed) regressed to 336 us with
// WRITE +10MB / FETCH +8MB = scratch spills: widening the scheduler window
// across merged phases extended live ranges past the register wall. Same law
// as round 7 (phase-ahead prefetch spilled). The per-phase LGKM0+sched_barrier
// pins act as register-pressure fences, not just sync. Round-10 schedule is
// the measured local optimum, bracketed from both sides:
//   16 barriers lockstep (r6): 355 us | 8 barriers + per-wave lgkm (r10):
//   315 us | 4 barriers relaxed (r11): 336 us.

#define TM 4096
#define TK 4096
#define TN 11008
#define GS 128
#define NG (TK / GS)
#define QZC (TN / 8)

// ---- phase-2 geometry (256x256 tile, BK=64, 8 waves / 512 threads) ----
#define BM2 256
#define BN2 256
#define BK2 64
#define NKT (TK / BK2)                    // 64 K-tiles
#define NBN (TN / BN2)                    // 43
#define GRID2 ((TM / BM2) * (TN / BN2))   // 16*43 = 688 (== 0 mod 8)

// ---- dequant geometry ----
#define DQN 256                           // n-columns per block
#define DQROW 136                         // LDS row stride in shorts (272 B)

// ---- legacy 128^2 geometry (fallback kernel) ----
#define BM 128
#define BN 128
#define BK 32

#define XB_BYTES ((size_t)TM * TK * 2)            // 33,554,432
#define WT_BYTES ((size_t)TN * TK * 2)            // 90,177,536
#define WS_NEED  (XB_BYTES + WT_BYTES)

typedef __attribute__((ext_vector_type(8))) short short8;
typedef __attribute__((ext_vector_type(4))) float floatx4;

union S8U { short8 v; unsigned u[4]; };

__device__ __forceinline__ unsigned short f2bf_rn(float f) {
    unsigned u = __builtin_bit_cast(unsigned, f);
    u += 0x7FFFu + ((u >> 16) & 1u);
    return (unsigned short)(u >> 16);
}
__device__ __forceinline__ unsigned pack2(float a, float b) {
    return (unsigned)f2bf_rn(a) | ((unsigned)f2bf_rn(b) << 16);
}

// ---------------- Phase 1a: X fp32 -> bf16 ----------------
__global__ __launch_bounds__(256)
void conv_x(const float* __restrict__ X, unsigned short* __restrict__ Xb)
{
    const size_t i = ((size_t)blockIdx.x * 256 + threadIdx.x) * 8;  // 8 floats/thread
    floatx4 v0 = *(const floatx4*)(X + i);
    floatx4 v1 = *(const floatx4*)(X + i + 4);
    S8U o;
    o.u[0] = pack2(v0[0], v0[1]); o.u[1] = pack2(v0[2], v0[3]);
    o.u[2] = pack2(v1[0], v1[1]); o.u[3] = pack2(v1[2], v1[3]);
    *(short8*)(Xb + i) = o.v;
}

// ---------------- Phase 1b: dequant qweight -> bf16 W^T[N][K] ----------------
// Coalesced QW reads (lane-consecutive n) + LDS transpose (272 B row stride)
// + 256B-per-16-lane output store pattern. (round-9 verified)
__global__ __launch_bounds__(256)
void dequant_w(const int* __restrict__ QW, const int* __restrict__ QZ,
               const float* __restrict__ SC, unsigned short* __restrict__ Wt)
{
    __shared__ __align__(16) short lds[DQN * DQROW];   // 69,632 B

    const int g  = blockIdx.x % NG;           // k-group
    const int n0 = (blockIdx.x / NG) * DQN;   // n-tile base
    const int t  = threadIdx.x;
    const int n  = n0 + t;

    const float s = SC[(size_t)g * TN + n];
    const int z = (int)(((unsigned)QZ[g * QZC + (n >> 3)] >> ((n & 7) * 4)) & 15u) + 1;
    const float zc = -s * (float)z;

    #pragma unroll
    for (int i = 0; i < 16; ++i) {
        const unsigned q = (unsigned)QW[(size_t)(g * 16 + i) * TN + n];  // coalesced
        const unsigned qe = q & 0x0F0F0F0Fu;          // nibbles 0,2,4,6
        const unsigned qo = (q >> 4) & 0x0F0F0F0Fu;   // nibbles 1,3,5,7
        S8U vv;
        #pragma unroll
        for (int jj = 0; jj < 4; ++jj) {
            const float w0 = (float)((qe >> (8 * jj)) & 0xFFu);
            const float w1 = (float)((qo >> (8 * jj)) & 0xFFu);
            vv.u[jj] = pack2(fmaf(w0, s, zc), fmaf(w1, s, zc));
        }
        *(short8*)(lds + t * DQROW + i * 8) = vv.v;
    }
    __syncthreads();

    const int c  = t & 15;          // pack chunk within group
    const int r0 = t >> 4;          // row base
    #pragma unroll
    for (int j = 0; j < 16; ++j) {
        const int nl = r0 + 16 * j;
        const short8 v = *(const short8*)(lds + nl * DQROW + c * 8);
        *(short8*)(Wt + (size_t)(n0 + nl) * TK + g * 128 + c * 8) = v;
    }
}

// ---------------- Phase 2: 256^2 8-phase bf16 GEMM ----------------
#define GLDS(gp, lp) __builtin_amdgcn_global_load_lds( \
    (const __attribute__((address_space(1))) void*)(gp), \
    (__attribute__((address_space(3))) void*)(lp), 16, 0, 0)

// op: 0=A, 1=B. half: 0 = rows [0,128), 1 = rows [128,256).
#define STAGE(op, gptr, buf, half, kt) do {                                   \
    const unsigned short* _g = (gptr) + (size_t)(half) * 128 * TK             \
                                      + (size_t)(kt) * BK2;                   \
    short* _l = &sh[buf][op][(half) * 8192 + ldst];                           \
    GLDS(_g, _l);                                                             \
    GLDS(_g + (size_t)64 * TK, _l + 4096);                                    \
} while (0)

// swizzled fragment reads: global 16B-chunk c sits at LDS slot c ^ (row&7)
#define RDA(buf, mi, ks) (*(const short8*)&sh[buf][0][ \
    (wr * 128 + (mi) * 16 + l16) * 64 + ((((ks) << 2) | quad) ^ swz) * 8])
#define RDB(buf, ni, ks) (*(const short8*)&sh[buf][1][ \
    (wc * 64 + (ni) * 16 + l16) * 64 + ((((ks) << 2) | quad) ^ swz) * 8])

#define BARRIER __builtin_amdgcn_s_barrier()
#define LGKM0 do { asm volatile("s_waitcnt lgkmcnt(0)" ::: "memory");         \
                   __builtin_amdgcn_sched_barrier(0); } while (0)
#define VMW4  asm volatile("s_waitcnt vmcnt(4)" ::: "memory")

template<int MI0, int NI0>
__device__ __forceinline__ void mfma_quad(floatx4 (&acc)[8][4],
                                          const short8 (&a)[4][2],
                                          const short8 (&b)[4][2]) {
    __builtin_amdgcn_s_setprio(1);
    #pragma unroll
    for (int m = 0; m < 4; ++m)
        #pragma unroll
        for (int n = 0; n < 2; ++n)
            #pragma unroll
            for (int ks = 0; ks < 2; ++ks)
                acc[MI0 + m][NI0 + n] = __builtin_amdgcn_mfma_f32_16x16x32_bf16(
                    a[m][ks], b[NI0 + n][ks], acc[MI0 + m][NI0 + n], 0, 0, 0);
    __builtin_amdgcn_s_setprio(0);
}

__global__ __launch_bounds__(512, 2)
void gemm_8ph(const unsigned short* __restrict__ A,   // bf16 [TM][TK]
              const unsigned short* __restrict__ Bt,  // bf16 [TN][TK]
              const float* __restrict__ BIAS,         // fp32 [TN]
              float* __restrict__ OUT)                // fp32 [TM][TN]
{
    __shared__ __align__(16) short sh[2][2][BM2 * BK2];   // 128 KiB

    const int tid  = threadIdx.x;
    const int lane = tid & 63;
    const int wave = tid >> 6;          // 0..7
    const int wr   = wave >> 2;         // 0..1 (M half)
    const int wc   = wave & 3;          // 0..3 (N quarter)
    const int quad = lane >> 4;
    const int l16  = lane & 15;
    const int swz  = l16 & 7;

    // T1: bijective XCD chunk swizzle (688 = 8 * 86); bn fastest -> A reuse in L2
    const int bid  = blockIdx.x;
    const int wgid = (bid & 7) * (GRID2 / 8) + (bid >> 3);
    const int bm = wgid / NBN;
    const int bn = wgid % NBN;

    // staging: LDS dest linear (base + lane*16B); global source pre-swizzled
    const int srow = wave * 8 + (lane >> 3);            // 0..63
    const int scol = 8 * ((lane & 7) ^ (lane >> 3));    // elements
    const unsigned short* Ag = A  + (size_t)(bm * BM2 + srow) * TK + scol;
    const unsigned short* Bg = Bt + (size_t)(bn * BN2 + srow) * TK + scol;
    const int ldst = wave * 512 + lane * 8;             // shorts

    floatx4 acc[8][4];
    #pragma unroll
    for (int i = 0; i < 8; ++i)
        #pragma unroll
        for (int j = 0; j < 4; ++j)
            acc[i][j] = (floatx4){0.f, 0.f, 0.f, 0.f};

    short8 a[4][2], b[4][2];

    // prologue: K-tile 0 full -> buf0; K-tile 1 B-halves -> buf1
    STAGE(0, Ag, 0, 0, 0); STAGE(0, Ag, 0, 1, 0);
    STAGE(1, Bg, 0, 0, 0); STAGE(1, Bg, 0, 1, 0);
    STAGE(1, Bg, 1, 0, 1); STAGE(1, Bg, 1, 1, 1);
    VMW4;       // drain K-tile 0's 8 loads; 4 (t1 B) stay in flight
    BARRIER;

    for (int it = 0; it < NKT / 2; ++it) {
        const int t  = 2 * it;
        const int t2 = (t + 2 < NKT) ? t + 2 : NKT - 1;   // tail stages: garbage,
        const int t3 = (t + 3 < NKT) ? t + 3 : NKT - 1;   // never consumed

        // ======== K-tile t (buf0) ========
        // p1: reads buf0 a03+b01; stage Ah0(t+1)->buf1 (disjoint from reads);
        //     per-wave lgkmcnt gate -> MFMA; single end barrier
        #pragma unroll
        for (int m = 0; m < 4; ++m) { a[m][0] = RDA(0, m, 0); a[m][1] = RDA(0, m, 1); }
        #pragma unroll
        for (int n = 0; n < 2; ++n) { b[n][0] = RDB(0, n, 0); b[n][1] = RDB(0, n, 1); }
        STAGE(0, Ag, 1, 0, t + 1);
        LGKM0;
        mfma_quad<0, 0>(acc, a, b);
        BARRIER;

        // p2: reads buf0 b23; stage Ah1(t+1)->buf1
        #pragma unroll
        for (int n = 2; n < 4; ++n) { b[n][0] = RDB(0, n, 0); b[n][1] = RDB(0, n, 1); }
        STAGE(0, Ag, 1, 1, t + 1);
        LGKM0;
        mfma_quad<0, 2>(acc, a, b);
        BARRIER;

        // p3: reads buf0 a47 (A-half); stage Bh0(t+2)->buf0 B-half (disjoint;
        //     buf0-B reads completed at every wave's p2 LGKM0, published by p2's
        //     end barrier)
        #pragma unroll
        for (int m = 0; m < 4; ++m) { a[m][0] = RDA(0, m + 4, 0); a[m][1] = RDA(0, m + 4, 1); }
        STAGE(1, Bg, 0, 0, t2);
        LGKM0;
        mfma_quad<4, 0>(acc, a, b);
        BARRIER;

        // p4: stage Bh1(t+2)->buf0; counted drain (leaves p3/p4 B(t+2) loads in
        //     flight) + mid barrier publishes it block-wide; MFMA after barrier
        STAGE(1, Bg, 0, 1, t2);
        VMW4;
        BARRIER;
        mfma_quad<4, 2>(acc, a, b);

        // ======== K-tile t+1 (buf1) ========
        // p5: reads buf1 a03+b01 (drained by p4's VMW4+barrier); stage
        //     Ah0(t+2)->buf0 (buf0-A reads done at p3's LGKM0)
        #pragma unroll
        for (int m = 0; m < 4; ++m) { a[m][0] = RDA(1, m, 0); a[m][1] = RDA(1, m, 1); }
        #pragma unroll
        for (int n = 0; n < 2; ++n) { b[n][0] = RDB(1, n, 0); b[n][1] = RDB(1, n, 1); }
        STAGE(0, Ag, 0, 0, t2);
        LGKM0;
        mfma_quad<0, 0>(acc, a, b);
        BARRIER;

        // p6: reads buf1 b23; stage Ah1(t+2)->buf0
        #pragma unroll
        for (int n = 2; n < 4; ++n) { b[n][0] = RDB(1, n, 0); b[n][1] = RDB(1, n, 1); }
        STAGE(0, Ag, 0, 1, t2);
        LGKM0;
        mfma_quad<0, 2>(acc, a, b);
        BARRIER;

        // p7: reads buf1 a47; stage Bh0(t+3)->buf1 B-half (buf1-B reads done
        //     at p6's LGKM0, published by p6's barrier)
        #pragma unroll
        for (int m = 0; m < 4; ++m) { a[m][0] = RDA(1, m + 4, 0); a[m][1] = RDA(1, m + 4, 1); }
        STAGE(1, Bg, 1, 0, t3);
        LGKM0;
        mfma_quad<4, 0>(acc, a, b);
        BARRIER;

        // p8: stage Bh1(t+3)->buf1; counted drain (drains A(t+2)+B(t+2) for
        //     next iter's p1) + mid barrier; MFMA; fall through to next iter
        STAGE(1, Bg, 1, 1, t3);
        VMW4;
        BARRIER;
        mfma_quad<4, 2>(acc, a, b);
    }

    // epilogue: C/D col=lane&15, row=quad*4+reg (dtype-independent layout)
    const int row0 = bm * BM2 + wr * 128 + quad * 4;
    const int col0 = bn * BN2 + wc * 64 + l16;
    #pragma unroll
    for (int ni = 0; ni < 4; ++ni) {
        const int col = col0 + ni * 16;
        const float bv = BIAS[col];
        #pragma unroll
        for (int mi = 0; mi < 8; ++mi) {
            #pragma unroll
            for (int r = 0; r < 4; ++r) {
                const int row = row0 + mi * 16 + r;
                OUT[(size_t)row * TN + col] = acc[mi][ni][r] + bv;
            }
        }
    }
}

// ---------------- Fallback: fused kernel (known-good, ws too small) ----------
__global__ __launch_bounds__(256)
void gemm_fused_fallback(const float* __restrict__ X, const int* __restrict__ QW,
                         const int* __restrict__ QZ, const float* __restrict__ SC,
                         const float* __restrict__ BIAS, float* __restrict__ OUT)
{
    __shared__ __align__(16) short As[BM * BK];
    __shared__ __align__(16) short Bs[BN * BK];

    const int tid  = threadIdx.x;
    const int lane = tid & 63;
    const int wave = tid >> 6;
    const int bm = blockIdx.x / (TN / BN);
    const int bn = blockIdx.x % (TN / BN);
    const int wm = (wave & 1) * 64;
    const int wn = (wave >> 1) * 64;
    const int quad = lane >> 4;
    const int l16  = lane & 15;

    const int a_r = tid >> 2;
    const int a_c = (tid & 3) * 8;
    const float* agp = X + (size_t)(bm * BM + a_r) * TK + a_c;
    short* alp = As + a_r * BK + a_c;

    const int b_n = tid & 127;
    const int b_p = tid >> 7;
    const int n_g = bn * BN + b_n;
    const int zsh = (n_g & 7) * 4;

    floatx4 acc[4][4];
    #pragma unroll
    for (int i = 0; i < 4; ++i)
        #pragma unroll
        for (int j = 0; j < 4; ++j)
            acc[i][j] = (floatx4){0.f, 0.f, 0.f, 0.f};

    for (int g = 0; g < NG; ++g) {
        const float s = SC[(size_t)g * TN + n_g];
        const int z = (int)(((unsigned)QZ[g * QZC + (n_g >> 3)] >> zsh) & 15u) + 1;
        const float zc = -s * (float)z;

        #pragma unroll
        for (int t = 0; t < GS / BK; ++t) {
            const int k0 = g * GS + t * BK;
            floatx4 v0 = *(const floatx4*)(agp + k0);
            floatx4 v1 = *(const floatx4*)(agp + k0 + 4);
            floatx4 v2 = *(const floatx4*)(agp + (size_t)64 * TK + k0);
            floatx4 v3 = *(const floatx4*)(agp + (size_t)64 * TK + k0 + 4);
            const unsigned q0 = (unsigned)QW[(size_t)(k0 / 8 + b_p)     * TN + n_g];
            const unsigned q1 = (unsigned)QW[(size_t)(k0 / 8 + b_p + 2) * TN + n_g];

            S8U aw0, aw1;
            aw0.u[0] = pack2(v0[0], v0[1]); aw0.u[1] = pack2(v0[2], v0[3]);
            aw0.u[2] = pack2(v1[0], v1[1]); aw0.u[3] = pack2(v1[2], v1[3]);
            aw1.u[0] = pack2(v2[0], v2[1]); aw1.u[1] = pack2(v2[2], v2[3]);
            aw1.u[2] = pack2(v3[0], v3[1]); aw1.u[3] = pack2(v3[2], v3[3]);
            *(short8*)alp = aw0.v;
            *(short8*)(alp + 64 * BK) = aw1.v;

            const unsigned qs[2] = {q0, q1};
            #pragma unroll
            for (int i = 0; i < 2; ++i) {
                const int p = b_p + i * 2;
                const unsigned q = qs[i];
                const unsigned qe = q & 0x0F0F0F0Fu;
                const unsigned qo = (q >> 4) & 0x0F0F0F0Fu;
                S8U vv;
                #pragma unroll
                for (int jj = 0; jj < 4; ++jj) {
                    const float w0 = (float)((qe >> (8 * jj)) & 0xFFu);
                    const float w1 = (float)((qo >> (8 * jj)) & 0xFFu);
                    vv.u[jj] = pack2(fmaf(w0, s, zc), fmaf(w1, s, zc));
                }
                *(short8*)(Bs + b_n * BK + p * 8) = vv.v;
            }

            __syncthreads();
            short8 af[4], bfr[4];
            #pragma unroll
            for (int i = 0; i < 4; ++i) {
                af[i]  = *(const short8*)(As + (wm + i * 16 + l16) * BK + quad * 8);
                bfr[i] = *(const short8*)(Bs + (wn + i * 16 + l16) * BK + quad * 8);
            }
            #pragma unroll
            for (int mi = 0; mi < 4; ++mi)
                #pragma unroll
                for (int ni = 0; ni < 4; ++ni)
                    acc[mi][ni] = __builtin_amdgcn_mfma_f32_16x16x32_bf16(
                        af[mi], bfr[ni], acc[mi][ni], 0, 0, 0);
            __syncthreads();
        }
    }

    const int col0 = bn * BN + wn + l16;
    const int row0 = bm * BM + wm + quad * 4;
    #pragma unroll
    for (int ni = 0; ni < 4; ++ni) {
        const int col = col0 + ni * 16;
        const float bv = BIAS[col];
        #pragma unroll
        for (int mi = 0; mi < 4; ++mi) {
            #pragma unroll
            for (int r = 0; r < 4; ++r) {
                const int row = row0 + mi * 16 + r;
                OUT[(size_t)row * TN + col] = acc[mi][ni][r] + bv;
            }
        }
    }
}

extern "C" void kernel_launch(void* const* d_in, const int* in_sizes, int n_in,
                              void* d_out, int out_size, void* d_ws, size_t ws_size,
                              hipStream_t stream) {
    // Resolve inputs by element count (all distinct); fall back to dict order.
    const void* px = nullptr; const void* pqw = nullptr; const void* pqz = nullptr;
    const void* psc = nullptr; const void* pbi = nullptr;
    for (int i = 0; i < n_in; ++i) {
        switch (in_sizes[i]) {
            case 16777216: px  = d_in[i]; break;  // x
            case 5636096:  pqw = d_in[i]; break;  // qweight
            case 352256:   psc = d_in[i]; break;  // scales
            case 44032:    pqz = d_in[i]; break;  // qzeros
            case 11008:    pbi = d_in[i]; break;  // bias
            default: break;                        // g_idx unused
        }
    }
    if (!px)  px  = d_in[0];
    if (!pqw) pqw = d_in[1];
    if (!pqz) pqz = d_in[2];
    if (!psc) psc = d_in[3];
    if (!pbi) pbi = d_in[5];

    if (ws_size >= WS_NEED) {
        unsigned short* Xb = (unsigned short*)d_ws;
        unsigned short* Wt = (unsigned short*)((char*)d_ws + XB_BYTES);

        conv_x<<<dim3(TM * TK / 8 / 256), 256, 0, stream>>>((const float*)px, Xb);
        dequant_w<<<dim3(NG * (TN / DQN)), 256, 0, stream>>>(
            (const int*)pqw, (const int*)pqz, (const float*)psc, Wt);
        gemm_8ph<<<dim3(GRID2), 512, 0, stream>>>(
            Xb, Wt, (const float*)pbi, (float*)d_out);
    } else {
        gemm_fused_fallback<<<dim3((TM / BM) * (TN / BN)), 256, 0, stream>>>(
            (const float*)px, (const int*)pqw, (const int*)pqz,
            (const float*)psc, (const float*)pbi, (float*)d_out);
    }
}